// Round 9
// baseline (285.550 us; speedup 1.0000x reference)
//
#include <hip/hip_runtime.h>

#define D 100
#define YSTRIDE 128   // bf16 row stride in elements (256 B = 64 uints)
#define BSHIFT 7      // 128 dst nodes per bucket
#define BSIZE 128
#define BMASK 127
#define NBKMAX 512    // supports N <= 65536
#define EPB 2048      // edges per block in bucket passes
#define DCAP 4096     // per-bucket staging capacity in phase D

typedef __attribute__((ext_vector_type(8))) short bf8v;
typedef __attribute__((ext_vector_type(4))) float f4v;

__device__ inline unsigned short f2bf(float f) {
    unsigned u = __float_as_uint(f);
    return (unsigned short)((u + 0x7fffu + ((u >> 16) & 1u)) >> 16);  // RNE
}
__device__ inline float bflo(unsigned v) { return __uint_as_float(v << 16); }
__device__ inline float bfhi(unsigned v) { return __uint_as_float(v & 0xffff0000u); }
// fp8 e4m3 (OCP on gfx950) helpers
__device__ inline unsigned short pk8(float a, float b) {
    return (unsigned short)(__builtin_amdgcn_cvt_pk_fp8_f32(a, b, 0, false) & 0xffff);
}
__device__ inline float up8lo(unsigned v) { return __builtin_amdgcn_cvt_f32_fp8((int)v, 0); }
__device__ inline float up8hi(unsigned v) { return __builtin_amdgcn_cvt_f32_fp8((int)v, 1); }

// exclusive scan of a[0..512) in LDS, t[256] scratch; 256 threads
__device__ inline void scan512_excl(int* a, int* t, int tid) {
    int v0 = a[2 * tid], v1 = a[2 * tid + 1];
    t[tid] = v0 + v1;
    __syncthreads();
    for (int off = 1; off < 256; off <<= 1) {
        int u = (tid >= off) ? t[tid - off] : 0;
        __syncthreads();
        t[tid] += u;
        __syncthreads();
    }
    int base = (tid ? t[tid - 1] : 0);
    a[2 * tid]     = base;
    a[2 * tid + 1] = base + v0;
    __syncthreads();
}

// ---------------- fused preamble: pack x0->fp8 half-rows | bucketA | W prepack ----------------
// s8 half-layout: s8[(half*N + node)*16 + qi] (uint). Row = 16 uints = 64 B = 1 sector.
// half h covers dims [h*50, h*50+50); byte b of the row = dim h*50+b (b<50), else 0.
// P[((l*7+nt)*4+kt)*64+lane] = 8 bf16 of M[nt*16+(lane&15)][kt*32+(lane>>4)*8+j],
//   M = W1 (l=0) or Wc=W2*W1 computed on the fly (l=1).
__global__ __launch_bounds__(256) void k_pre(const float* __restrict__ x0, const float* __restrict__ W,
                                             unsigned* __restrict__ s8, unsigned short* __restrict__ P,
                                             int* __restrict__ bcnt, const int* __restrict__ dst,
                                             int N, int E, int nbk, int packb, int ablk) {
    __shared__ int lhist[NBKMAX];
    int tid = threadIdx.x;
    int bx = blockIdx.x;

    if (bx < packb) {
        // ---- pack ----
        int t = bx * 256 + tid;
        if (t >= N * 32) return;
        int node = t >> 5, q = t & 31;
        int half = q >> 4, qi = q & 15;
        float f[4];
#pragma unroll
        for (int j = 0; j < 4; j++) {
            int dd = 4 * qi + j;
            f[j] = (dd < 50) ? x0[(long)node * D + half * 50 + dd] : 0.f;
        }
        unsigned p = (unsigned)pk8(f[0], f[1]) | ((unsigned)pk8(f[2], f[3]) << 16);
        s8[((long)half * N + node) * 16 + qi] = p;
    } else if (bx < packb + ablk) {
        // ---- bucketA ----
        int base = (bx - packb) * EPB;
        int count = min(EPB, E - base);
        for (int i = tid; i < NBKMAX; i += 256) lhist[i] = 0;
        __syncthreads();
        for (int i = tid; i < count; i += 256) atomicAdd(&lhist[dst[base + i] >> BSHIFT], 1);
        __syncthreads();
        for (int b = tid; b < nbk; b += 256)
            if (lhist[b]) atomicAdd(&bcnt[b], lhist[b]);
    } else {
        // ---- W prepack (Wc on the fly) ----
        int t = (bx - packb - ablk) * 256 + tid;
        int wtot = 2 * 7 * 4 * 64;
        if (t >= wtot) return;
        int lane = t & 63;
        int r = t >> 6;
        int kt = r & 3;
        int r2 = r >> 2;
        int nt = r2 % 7;
        int l  = r2 / 7;
        int ng = nt * 16 + (lane & 15);
        int k0 = kt * 32 + (lane >> 4) * 8;
        unsigned short u[8];
#pragma unroll
        for (int j = 0; j < 8; j++) {
            int k = k0 + j;
            float mv = 0.f;
            if (ng < D && k < D) {
                if (l == 0) {
                    mv = W[(long)ng * D + k];
                } else {
                    const float* w2 = W + D * D + (long)ng * D;
                    for (int kk = 0; kk < D; kk++) mv += w2[kk] * W[(long)kk * D + k];
                }
            }
            u[j] = f2bf(mv);
        }
        uint4 o;
        o.x = (unsigned)u[0] | ((unsigned)u[1] << 16);
        o.y = (unsigned)u[2] | ((unsigned)u[3] << 16);
        o.z = (unsigned)u[4] | ((unsigned)u[5] << 16);
        o.w = (unsigned)u[6] | ((unsigned)u[7] << 16);
        *(uint4*)(P + (long)t * 8) = o;
    }
}

// ---------------- Phase B ----------------
__global__ __launch_bounds__(256) void k_scanB(const int* __restrict__ bucket_cnt,
                                               int* __restrict__ bucket_off,
                                               int* __restrict__ bucket_cur, int nbk, int E) {
    __shared__ int a[NBKMAX], t[256];
    int tid = threadIdx.x;
    a[tid]       = (tid < nbk) ? bucket_cnt[tid] : 0;
    a[tid + 256] = (tid + 256 < nbk) ? bucket_cnt[tid + 256] : 0;
    __syncthreads();
    scan512_excl(a, t, tid);
    if (tid < nbk)       { bucket_off[tid] = a[tid];             bucket_cur[tid] = a[tid]; }
    if (tid + 256 < nbk) { bucket_off[tid + 256] = a[tid + 256]; bucket_cur[tid + 256] = a[tid + 256]; }
    if (tid == 0) bucket_off[nbk] = E;
}

// ---------------- Phase C ----------------
__global__ __launch_bounds__(256) void k_bucketC(const int* __restrict__ src,
                                                 const int* __restrict__ dst,
                                                 int* __restrict__ bucket_cur,
                                                 unsigned* __restrict__ ebuf, int E, int nbk) {
    __shared__ int lhist[NBKMAX], lstart[NBKMAX], runS[NBKMAX], t[256];
    __shared__ unsigned stage[EPB];
    int tid = threadIdx.x;
    int base = blockIdx.x * EPB;
    int count = min(EPB, E - base);

    for (int i = tid; i < NBKMAX; i += 256) lhist[i] = 0;
    __syncthreads();
    for (int i = tid; i < count; i += 256) atomicAdd(&lhist[dst[base + i] >> BSHIFT], 1);
    __syncthreads();
    for (int i = tid; i < NBKMAX; i += 256) lstart[i] = lhist[i];
    __syncthreads();
    scan512_excl(lstart, t, tid);
    for (int b = tid; b < nbk; b += 256) {
        int c = lhist[b];
        runS[b] = c ? atomicAdd(&bucket_cur[b], c) : 0;
    }
    __syncthreads();
    for (int i = tid; i < NBKMAX; i += 256) lhist[i] = 0;
    __syncthreads();
    for (int i = tid; i < count; i += 256) {
        int dv = dst[base + i];
        int sv = src[base + i];
        int b = dv >> BSHIFT;
        int r = atomicAdd(&lhist[b], 1);
        stage[lstart[b] + r] = ((unsigned)(dv & BMASK) << 16) | (unsigned)sv;
    }
    __syncthreads();
    int wave = tid >> 6, lane = tid & 63;
    for (int b = wave; b < nbk; b += 4) {
        int c = lhist[b], ls = lstart[b], rs = runS[b];
        for (int j = lane; j < c; j += 64) ebuf[rs + j] = stage[ls + j];
    }
}

// ---------------- Phase D ----------------
__global__ __launch_bounds__(256) void k_bucketD(const unsigned* __restrict__ ebuf,
                                                 const int* __restrict__ bucket_off,
                                                 int* __restrict__ col, int* __restrict__ rowptr,
                                                 int N, int nbk, int E) {
    __shared__ int lh[BSIZE], ls[BSIZE];
    __shared__ int colStage[DCAP];
    int b = blockIdx.x;
    int tid = threadIdx.x;
    int beg = bucket_off[b], end = bucket_off[b + 1];
    int cnt = end - beg;

    if (tid < BSIZE) lh[tid] = 0;
    __syncthreads();
    for (int i = tid; i < cnt; i += 256) atomicAdd(&lh[ebuf[beg + i] >> 16], 1);
    __syncthreads();
    if (tid < BSIZE) ls[tid] = lh[tid];
    __syncthreads();
    for (int off = 1; off < BSIZE; off <<= 1) {
        int v = (tid >= off && tid < BSIZE) ? ls[tid - off] : 0;
        __syncthreads();
        if (tid < BSIZE) ls[tid] += v;
        __syncthreads();
    }
    if (tid < BSIZE) ls[tid] -= lh[tid];
    __syncthreads();
    int d0 = b * BSIZE;
    if (tid < BSIZE && d0 + tid < N) rowptr[d0 + tid] = beg + ls[tid];
    if (b == nbk - 1 && tid == 0) rowptr[N] = E;
    if (tid < BSIZE) lh[tid] = 0;
    __syncthreads();
    if (cnt <= DCAP) {
        for (int i = tid; i < cnt; i += 256) {
            unsigned p = ebuf[beg + i];
            int r = p >> 16, s = (int)(p & 0xffffu);
            int k = atomicAdd(&lh[r], 1);
            colStage[ls[r] + k] = s;
        }
        __syncthreads();
        for (int i = tid; i < cnt; i += 256) col[beg + i] = colStage[i];
    } else {
        for (int i = tid; i < cnt; i += 256) {
            unsigned p = ebuf[beg + i];
            int r = p >> 16, s = (int)(p & 0xffffu);
            int k = atomicAdd(&lh[r], 1);
            col[beg + ls[r] + k] = s;
        }
    }
}

// ---------------- half-dim SpMM on fp8 half-rows ----------------
// g8h: fp8 half-rows for half h, 64 B (1 sector) each, 32 ushorts/row.
// Lane l<25 owns dims {h*50+2l, h*50+2l+1}. Lanes >=25 duplicate lane 24 (discarded).
// self16 (optional): bf16 full rows for higher-precision self term.
// Writes o16 uints [h*25, h*25+25) of each row; h==1 also zeroes pad uints [50,64).
// o8h (optional): fp8 half-rows for the next gather.
__global__ __launch_bounds__(256) void k_spmm_h(const unsigned short* __restrict__ g8h,
                                                const int* __restrict__ rowptr,
                                                const int* __restrict__ col,
                                                const unsigned* __restrict__ self16,
                                                unsigned short* __restrict__ o8h,
                                                unsigned* __restrict__ o16,
                                                int h, int N) {
    int wave = threadIdx.x >> 6;
    int lane = threadIdx.x & 63;
    int leff = (lane < 25) ? lane : 24;
    int d0 = (blockIdx.x * 4 + wave) * 2;
    if (d0 >= N) return;
    int d1 = d0 + 1;
    bool has1 = d1 < N;

    int b0 = __builtin_amdgcn_readfirstlane(rowptr[d0]);
    int e0 = __builtin_amdgcn_readfirstlane(rowptr[d0 + 1]);
    int e1 = has1 ? __builtin_amdgcn_readfirstlane(rowptr[d1 + 1]) : e0;

    float ax0, ay0, ax1, ay1;
    if (self16) {
        unsigned sv0 = self16[(long)d0 * 64 + h * 25 + leff];
        ax0 = bflo(sv0); ay0 = bfhi(sv0);
        unsigned sv1 = self16[(long)(has1 ? d1 : d0) * 64 + h * 25 + leff];
        ax1 = bflo(sv1); ay1 = bfhi(sv1);
    } else {
        unsigned sv0 = g8h[(long)d0 * 32 + leff];
        ax0 = up8lo(sv0); ay0 = up8hi(sv0);
        unsigned sv1 = g8h[(long)(has1 ? d1 : d0) * 32 + leff];
        ax1 = up8lo(sv1); ay1 = up8hi(sv1);
    }

    for (int win = b0; win < e1; win += 64) {
        int m = e1 - win;
        if (m > 64) m = 64;
        int c = col[win + lane];  // lanes >= m load garbage; never consumed
        int j = 0;
        for (; j + 8 <= m; j += 8) {
            int s0 = __builtin_amdgcn_readlane(c, j);
            int s1 = __builtin_amdgcn_readlane(c, j + 1);
            int s2 = __builtin_amdgcn_readlane(c, j + 2);
            int s3 = __builtin_amdgcn_readlane(c, j + 3);
            int s4 = __builtin_amdgcn_readlane(c, j + 4);
            int s5 = __builtin_amdgcn_readlane(c, j + 5);
            int s6 = __builtin_amdgcn_readlane(c, j + 6);
            int s7 = __builtin_amdgcn_readlane(c, j + 7);
            unsigned v0 = g8h[(long)s0 * 32 + leff];
            unsigned v1 = g8h[(long)s1 * 32 + leff];
            unsigned v2 = g8h[(long)s2 * 32 + leff];
            unsigned v3 = g8h[(long)s3 * 32 + leff];
            unsigned v4 = g8h[(long)s4 * 32 + leff];
            unsigned v5 = g8h[(long)s5 * 32 + leff];
            unsigned v6 = g8h[(long)s6 * 32 + leff];
            unsigned v7 = g8h[(long)s7 * 32 + leff];
#pragma unroll
            for (int k = 0; k < 8; k++) {
                unsigned vv = (k == 0) ? v0 : (k == 1) ? v1 : (k == 2) ? v2 : (k == 3) ? v3
                            : (k == 4) ? v4 : (k == 5) ? v5 : (k == 6) ? v6 : v7;
                float w0 = (win + j + k < e0) ? 1.f : 0.f;  // wave-uniform select
                float w1 = 1.f - w0;
                float lx = up8lo(vv), ly = up8hi(vv);
                ax0 += lx * w0; ay0 += ly * w0;
                ax1 += lx * w1; ay1 += ly * w1;
            }
        }
        for (; j < m; j++) {
            int s = __builtin_amdgcn_readlane(c, j);
            unsigned vv = g8h[(long)s * 32 + leff];
            float w0 = (win + j < e0) ? 1.f : 0.f;
            float w1 = 1.f - w0;
            float lx = up8lo(vv), ly = up8hi(vv);
            ax0 += lx * w0; ay0 += ly * w0;
            ax1 += lx * w1; ay1 += ly * w1;
        }
    }

    float dinv0 = 1.f / (float)(e0 - b0 + 1);
    float dinv1 = 1.f / (float)(e1 - e0 + 1);
    float rx0 = ax0 * dinv0, ry0 = ay0 * dinv0;
    float rx1 = ax1 * dinv1, ry1 = ay1 * dinv1;

    if (lane < 25) {
        o16[(long)d0 * 64 + h * 25 + lane] = (unsigned)f2bf(rx0) | ((unsigned)f2bf(ry0) << 16);
        if (o8h) o8h[(long)d0 * 32 + lane] = pk8(rx0, ry0);
        if (has1) {
            o16[(long)d1 * 64 + h * 25 + lane] = (unsigned)f2bf(rx1) | ((unsigned)f2bf(ry1) << 16);
            if (o8h) o8h[(long)d1 * 32 + lane] = pk8(rx1, ry1);
        }
    } else if (h == 1 && lane < 39) {
        // zero pad uints [50,64) for the epilogue's full-row uint4 loads
        o16[(long)d0 * 64 + 25 + lane] = 0u;
        if (has1) o16[(long)d1 * 64 + 25 + lane] = 0u;
    }
}

// ---------------- fused epilogue: x1=u*W1^T, x2=v*Wc^T, norms, out ----------------
__global__ __launch_bounds__(256) void k_epi(const unsigned short* __restrict__ u16,
                                             const unsigned short* __restrict__ v16,
                                             const unsigned short* __restrict__ P,  // W1 then Wc frags
                                             const float* __restrict__ x0,
                                             float invlp1, float* __restrict__ out, int N) {
    int wave = threadIdx.x >> 6;
    int lane = threadIdx.x & 63;
    int quad = lane >> 4;
    int l16  = lane & 15;
    int rowbase = (blockIdx.x * 4 + wave) * 16;
    if (rowbase >= N) return;
    int arow = rowbase + l16;
    if (arow >= N) arow = N - 1;

    bf8v aU[4], aV[4];
    const unsigned short* ur = u16 + (long)arow * YSTRIDE;
    const unsigned short* vr = v16 + (long)arow * YSTRIDE;
#pragma unroll
    for (int kt = 0; kt < 4; kt++) {
        int k0 = kt * 32 + quad * 8;
        union { bf8v v; uint4 u; } a, b;
        a.u = *(const uint4*)(ur + k0);
        b.u = *(const uint4*)(vr + k0);
        aU[kt] = a.v;
        aV[kt] = b.v;
    }

    f4v accU[7], accV[7];
#pragma unroll
    for (int nt = 0; nt < 7; nt++) { accU[nt] = (f4v){0,0,0,0}; accV[nt] = (f4v){0,0,0,0}; }

    const uint4* bp = (const uint4*)P;
#pragma unroll
    for (int nt = 0; nt < 7; nt++) {
#pragma unroll
        for (int kt = 0; kt < 4; kt++) {
            union { uint4 u; bf8v v; } b1, b2;
            b1.u = bp[(nt * 4 + kt) * 64 + lane];
            b2.u = bp[(28 + nt * 4 + kt) * 64 + lane];
            accU[nt] = __builtin_amdgcn_mfma_f32_16x16x32_bf16(aU[kt], b1.v, accU[nt], 0, 0, 0);
            accV[nt] = __builtin_amdgcn_mfma_f32_16x16x32_bf16(aV[kt], b2.v, accV[nt], 0, 0, 0);
        }
    }

    float sU[4], sV[4];
#pragma unroll
    for (int i = 0; i < 4; i++) {
        float nu = 0.f, nv = 0.f;
#pragma unroll
        for (int nt = 0; nt < 7; nt++) {
            nu += accU[nt][i] * accU[nt][i];
            nv += accV[nt][i] * accV[nt][i];
        }
#pragma unroll
        for (int m = 1; m < 16; m <<= 1) {
            nu += __shfl_xor(nu, m);
            nv += __shfl_xor(nv, m);
        }
        sU[i] = invlp1 / fmaxf(sqrtf(nu), 1e-12f);
        sV[i] = invlp1 / fmaxf(sqrtf(nv), 1e-12f);
    }

#pragma unroll
    for (int nt = 0; nt < 7; nt++) {
        int cc = nt * 16 + l16;
        if (cc < D) {
#pragma unroll
            for (int i = 0; i < 4; i++) {
                int rr = rowbase + quad * 4 + i;
                if (rr < N) {
                    long idx = (long)rr * D + cc;
                    out[idx] = x0[idx] * invlp1 + accU[nt][i] * sU[i] + accV[nt][i] * sV[i];
                }
            }
        }
    }
}

// ---------------- launcher ----------------

extern "C" void kernel_launch(void* const* d_in, const int* in_sizes, int n_in,
                              void* d_out, int out_size, void* d_ws, size_t ws_size,
                              hipStream_t stream) {
    const float* features = (const float*)d_in[0];
    const float* W        = (const float*)d_in[1];
    const int*   src      = (const int*)d_in[2];
    const int*   dstv     = (const int*)d_in[3];

    int N = in_sizes[0] / D;            // 50000
    int E = in_sizes[2];                // 800000
    int L = in_sizes[1] / (D * D);      // 2 (composition assumes L==2)
    float invlp1 = 1.f / (float)(L + 1);
    int NBK = (N + BSIZE - 1) >> BSHIFT;

    char*  ws  = (char*)d_ws;
    size_t off = 0;
    auto alloc = [&](size_t bytes) -> void* {
        void* p = (void*)(ws + off);
        off += (bytes + 255) & ~(size_t)255;
        return p;
    };
    unsigned*       s8     = (unsigned*)alloc((size_t)2 * N * 16 * sizeof(unsigned));  // fp8 half-rows
    unsigned*       u8     = (unsigned*)alloc((size_t)2 * N * 16 * sizeof(unsigned));  // fp8 half-rows
    unsigned*       u16    = (unsigned*)alloc((size_t)N * 64 * sizeof(unsigned));      // bf16 rows
    unsigned*       v16    = (unsigned*)alloc((size_t)N * 64 * sizeof(unsigned));      // bf16 rows
    unsigned short* wpack  = (unsigned short*)alloc((size_t)2 * 7 * 4 * 64 * 8 * sizeof(unsigned short));
    unsigned*       ebuf   = (unsigned*)alloc((size_t)E * sizeof(unsigned));
    int*            colb   = (int*)alloc((size_t)E * sizeof(int));
    int*            rowptr = (int*)alloc((size_t)(N + 1) * sizeof(int));
    int*            bcnt   = (int*)alloc((size_t)NBKMAX * sizeof(int));
    int*            boff   = (int*)alloc((size_t)(NBKMAX + 1) * sizeof(int));
    int*            bcur   = (int*)alloc((size_t)NBKMAX * sizeof(int));

    int nebk  = (E + EPB - 1) / EPB;
    int wtot  = 2 * 7 * 4 * 64;
    int packb = (N * 32 + 255) / 256;
    int pblk  = (wtot + 255) / 256;

    hipMemsetAsync(bcnt, 0, (size_t)NBK * sizeof(int), stream);
    k_pre<<<packb + nebk + pblk, 256, 0, stream>>>(features, W, s8, wpack, bcnt, dstv,
                                                   N, E, NBK, packb, nebk);
    k_scanB<<<1, 256, 0, stream>>>(bcnt, boff, bcur, NBK, E);
    k_bucketC<<<nebk, 256, 0, stream>>>(src, dstv, bcur, ebuf, E, NBK);
    k_bucketD<<<NBK, 256, 0, stream>>>(ebuf, boff, colb, rowptr, N, NBK, E);

    int spmmblocks = (N + 7) / 8;  // 4 waves x 2 nodes per block
    const unsigned short* s8h0 = (const unsigned short*)s8;
    const unsigned short* s8h1 = (const unsigned short*)(s8 + (size_t)N * 16);
    unsigned short*       u8h0 = (unsigned short*)u8;
    unsigned short*       u8h1 = (unsigned short*)(u8 + (size_t)N * 16);

    // u = A*s0 (half 0), then v-half0 = A*u-half0 while u8h0 is L2-warm; repeat for half 1.
    k_spmm_h<<<spmmblocks, 256, 0, stream>>>(s8h0, rowptr, colb, (const unsigned*)nullptr,
                                             u8h0, u16, 0, N);
    k_spmm_h<<<spmmblocks, 256, 0, stream>>>(u8h0, rowptr, colb, u16,
                                             (unsigned short*)nullptr, v16, 0, N);
    k_spmm_h<<<spmmblocks, 256, 0, stream>>>(s8h1, rowptr, colb, (const unsigned*)nullptr,
                                             u8h1, u16, 1, N);
    k_spmm_h<<<spmmblocks, 256, 0, stream>>>(u8h1, rowptr, colb, u16,
                                             (unsigned short*)nullptr, v16, 1, N);

    int nrowtiles = (N + 15) / 16;
    int epiblocks = (nrowtiles + 3) / 4;
    k_epi<<<epiblocks, 256, 0, stream>>>((const unsigned short*)u16, (const unsigned short*)v16,
                                         wpack, features, invlp1, (float*)d_out, N);
}

// Round 10
// 207.979 us; speedup vs baseline: 1.3730x; 1.3730x over previous
//
#include <hip/hip_runtime.h>

#define D 100
#define YSTRIDE 128   // bf16 row stride in elements (256 B = 64 uints)
#define BSHIFT 7      // 128 dst nodes per bucket
#define BSIZE 128
#define BMASK 127
#define NBKMAX 512    // supports N <= 65536
#define EPB 2048      // edges per block in bucket passes
#define DCAP 4096     // per-bucket staging capacity in phase D

typedef __attribute__((ext_vector_type(8))) short bf8v;
typedef __attribute__((ext_vector_type(4))) float f4v;

__device__ inline unsigned short f2bf(float f) {
    unsigned u = __float_as_uint(f);
    return (unsigned short)((u + 0x7fffu + ((u >> 16) & 1u)) >> 16);  // RNE
}
__device__ inline float bflo(unsigned v) { return __uint_as_float(v << 16); }
__device__ inline float bfhi(unsigned v) { return __uint_as_float(v & 0xffff0000u); }
// fp8 e4m3 (OCP on gfx950) helpers
__device__ inline unsigned short pk8(float a, float b) {
    return (unsigned short)(__builtin_amdgcn_cvt_pk_fp8_f32(a, b, 0, false) & 0xffff);
}
__device__ inline float up8lo(unsigned v) { return __builtin_amdgcn_cvt_f32_fp8((int)v, 0); }
__device__ inline float up8hi(unsigned v) { return __builtin_amdgcn_cvt_f32_fp8((int)v, 1); }

// exclusive scan of a[0..512) in LDS, t[256] scratch; 256 threads
__device__ inline void scan512_excl(int* a, int* t, int tid) {
    int v0 = a[2 * tid], v1 = a[2 * tid + 1];
    t[tid] = v0 + v1;
    __syncthreads();
    for (int off = 1; off < 256; off <<= 1) {
        int u = (tid >= off) ? t[tid - off] : 0;
        __syncthreads();
        t[tid] += u;
        __syncthreads();
    }
    int base = (tid ? t[tid - 1] : 0);
    a[2 * tid]     = base;
    a[2 * tid + 1] = base + v0;
    __syncthreads();
}

// ---------------- fused preamble: pack x0->fp8 rows | bucketA | Wc=W2*W1 ----------------
// All three branches have uniform per-block work (no straggler blocks).
// s8 rows: 32 uints = 128 B = 1 cache line; uint q holds dims 4q..4q+3.
__global__ __launch_bounds__(256) void k_pre(const float* __restrict__ x0, const float* __restrict__ W,
                                             unsigned* __restrict__ s8, float* __restrict__ Wc,
                                             int* __restrict__ bcnt, const int* __restrict__ dst,
                                             int N, int E, int nbk, int packb, int ablk) {
    __shared__ int lhist[NBKMAX];
    int tid = threadIdx.x;
    int bx = blockIdx.x;

    if (bx < packb) {
        // ---- pack x0 -> fp8 full rows ----
        int t = bx * 256 + tid;
        if (t >= N * 32) return;
        int d = t >> 5, q = t & 31;
        unsigned p = 0u;
        if (q < D / 4) {
            float4 v = *(const float4*)(x0 + (long)d * D + q * 4);
            p = (unsigned)pk8(v.x, v.y) | ((unsigned)pk8(v.z, v.w) << 16);
        }
        s8[t] = p;
    } else if (bx < packb + ablk) {
        // ---- bucketA: LDS-staged bucket histogram ----
        int base = (bx - packb) * EPB;
        int count = min(EPB, E - base);
        for (int i = tid; i < NBKMAX; i += 256) lhist[i] = 0;
        __syncthreads();
        for (int i = tid; i < count; i += 256) atomicAdd(&lhist[dst[base + i] >> BSHIFT], 1);
        __syncthreads();
        for (int b = tid; b < nbk; b += 256)
            if (lhist[b]) atomicAdd(&bcnt[b], lhist[b]);
    } else {
        // ---- Wc = W2 * W1 (one thread per output element, uniform work) ----
        int t = (bx - packb - ablk) * 256 + tid;
        if (t >= D * D) return;
        int i = t / D, j = t - i * D;
        const float* w2 = W + D * D + (long)i * D;
        float s = 0.f;
        for (int k = 0; k < D; k++) s += w2[k] * W[(long)k * D + j];
        Wc[t] = s;
    }
}

// ---------------- fused: scanB (block 0) | W prepack (blocks 1..14) ----------------
// P[((l*7+nt)*4+kt)*64+lane] = 8 bf16 of M[nt*16+(lane&15)][kt*32+(lane>>4)*8+j],
//   M = W1 (l=0) or Wc (l=1).
__global__ __launch_bounds__(256) void k_scanB_prep(const int* __restrict__ bucket_cnt,
                                                    int* __restrict__ bucket_off,
                                                    int* __restrict__ bucket_cur, int nbk, int E,
                                                    const float* __restrict__ W1,
                                                    const float* __restrict__ Wc,
                                                    unsigned short* __restrict__ P, int wtot) {
    int tid = threadIdx.x;
    if (blockIdx.x == 0) {
        __shared__ int a[NBKMAX], t[256];
        a[tid]       = (tid < nbk) ? bucket_cnt[tid] : 0;
        a[tid + 256] = (tid + 256 < nbk) ? bucket_cnt[tid + 256] : 0;
        __syncthreads();
        scan512_excl(a, t, tid);
        if (tid < nbk)       { bucket_off[tid] = a[tid];             bucket_cur[tid] = a[tid]; }
        if (tid + 256 < nbk) { bucket_off[tid + 256] = a[tid + 256]; bucket_cur[tid + 256] = a[tid + 256]; }
        if (tid == 0) bucket_off[nbk] = E;
    } else {
        int t = (blockIdx.x - 1) * 256 + tid;
        if (t >= wtot) return;
        int lane = t & 63;
        int r = t >> 6;
        int kt = r & 3;
        int r2 = r >> 2;
        int nt = r2 % 7;
        int l  = r2 / 7;
        const float* M = (l == 0) ? W1 : Wc;
        int ng = nt * 16 + (lane & 15);
        int k0 = kt * 32 + (lane >> 4) * 8;
        unsigned short u[8];
#pragma unroll
        for (int j = 0; j < 8; j++) {
            int k = k0 + j;
            u[j] = (ng < D && k < D) ? f2bf(M[(long)ng * D + k]) : (unsigned short)0;
        }
        uint4 o;
        o.x = (unsigned)u[0] | ((unsigned)u[1] << 16);
        o.y = (unsigned)u[2] | ((unsigned)u[3] << 16);
        o.z = (unsigned)u[4] | ((unsigned)u[5] << 16);
        o.w = (unsigned)u[6] | ((unsigned)u[7] << 16);
        *(uint4*)(P + (long)t * 8) = o;
    }
}

// ---------------- Phase C: bucketed edge dump, coalesced writes ----------------
// ebuf entry: (dst & 127) << 16 | src   (requires N <= 65536)
__global__ __launch_bounds__(256) void k_bucketC(const int* __restrict__ src,
                                                 const int* __restrict__ dst,
                                                 int* __restrict__ bucket_cur,
                                                 unsigned* __restrict__ ebuf, int E, int nbk) {
    __shared__ int lhist[NBKMAX], lstart[NBKMAX], runS[NBKMAX], t[256];
    __shared__ unsigned stage[EPB];
    int tid = threadIdx.x;
    int base = blockIdx.x * EPB;
    int count = min(EPB, E - base);

    for (int i = tid; i < NBKMAX; i += 256) lhist[i] = 0;
    __syncthreads();
    for (int i = tid; i < count; i += 256) atomicAdd(&lhist[dst[base + i] >> BSHIFT], 1);
    __syncthreads();
    for (int i = tid; i < NBKMAX; i += 256) lstart[i] = lhist[i];
    __syncthreads();
    scan512_excl(lstart, t, tid);
    for (int b = tid; b < nbk; b += 256) {
        int c = lhist[b];
        runS[b] = c ? atomicAdd(&bucket_cur[b], c) : 0;
    }
    __syncthreads();
    for (int i = tid; i < NBKMAX; i += 256) lhist[i] = 0;
    __syncthreads();
    for (int i = tid; i < count; i += 256) {
        int dv = dst[base + i];
        int sv = src[base + i];
        int b = dv >> BSHIFT;
        int r = atomicAdd(&lhist[b], 1);
        stage[lstart[b] + r] = ((unsigned)(dv & BMASK) << 16) | (unsigned)sv;
    }
    __syncthreads();
    int wave = tid >> 6, lane = tid & 63;
    for (int b = wave; b < nbk; b += 4) {
        int c = lhist[b], ls = lstart[b], rs = runS[b];
        for (int j = lane; j < c; j += 64) ebuf[rs + j] = stage[ls + j];
    }
}

// ---------------- Phase D: per-bucket CSR finalize (coalesced) ----------------
__global__ __launch_bounds__(256) void k_bucketD(const unsigned* __restrict__ ebuf,
                                                 const int* __restrict__ bucket_off,
                                                 int* __restrict__ col, int* __restrict__ rowptr,
                                                 int N, int nbk, int E) {
    __shared__ int lh[BSIZE], ls[BSIZE];
    __shared__ int colStage[DCAP];
    int b = blockIdx.x;
    int tid = threadIdx.x;
    int beg = bucket_off[b], end = bucket_off[b + 1];
    int cnt = end - beg;

    if (tid < BSIZE) lh[tid] = 0;
    __syncthreads();
    for (int i = tid; i < cnt; i += 256) atomicAdd(&lh[ebuf[beg + i] >> 16], 1);
    __syncthreads();
    if (tid < BSIZE) ls[tid] = lh[tid];
    __syncthreads();
    for (int off = 1; off < BSIZE; off <<= 1) {
        int v = (tid >= off && tid < BSIZE) ? ls[tid - off] : 0;
        __syncthreads();
        if (tid < BSIZE) ls[tid] += v;
        __syncthreads();
    }
    if (tid < BSIZE) ls[tid] -= lh[tid];
    __syncthreads();
    int d0 = b * BSIZE;
    if (tid < BSIZE && d0 + tid < N) rowptr[d0 + tid] = beg + ls[tid];
    if (b == nbk - 1 && tid == 0) rowptr[N] = E;
    if (tid < BSIZE) lh[tid] = 0;
    __syncthreads();
    if (cnt <= DCAP) {
        for (int i = tid; i < cnt; i += 256) {
            unsigned p = ebuf[beg + i];
            int r = p >> 16, s = (int)(p & 0xffffu);
            int k = atomicAdd(&lh[r], 1);
            colStage[ls[r] + k] = s;
        }
        __syncthreads();
        for (int i = tid; i < cnt; i += 256) col[beg + i] = colStage[i];
    } else {
        for (int i = tid; i < cnt; i += 256) {
            unsigned p = ebuf[beg + i];
            int r = p >> 16, s = (int)(p & 0xffffu);
            int k = atomicAdd(&lh[r], 1);
            col[beg + ls[r] + k] = s;
        }
    }
}

// ---------------- pure SpMM on fp8 rows: o = (g[d] + sum g[src]) / deg ----------------
// g8: fp8 e4m3 rows, 128 B (1 cache line) each; lane owns dims {2l, 2l+1} (ushort).
// self16 (optional): bf16 rows for the self term (higher precision).
// Outputs: o16 bf16 rows always; o8 fp8 rows if write8.
__global__ __launch_bounds__(256) void k_spmm(const unsigned short* __restrict__ g8,
                                              const int* __restrict__ rowptr,
                                              const int* __restrict__ col,
                                              const unsigned* __restrict__ self16,
                                              unsigned short* __restrict__ o8,
                                              unsigned* __restrict__ o16,
                                              int write8, int N) {
    int wave = threadIdx.x >> 6;
    int lane = threadIdx.x & 63;
    int d0 = (blockIdx.x * 4 + wave) * 2;
    if (d0 >= N) return;
    int d1 = d0 + 1;
    bool has1 = d1 < N;

    int b0 = __builtin_amdgcn_readfirstlane(rowptr[d0]);
    int e0 = __builtin_amdgcn_readfirstlane(rowptr[d0 + 1]);
    int e1 = has1 ? __builtin_amdgcn_readfirstlane(rowptr[d1 + 1]) : e0;

    float ax0, ay0, ax1, ay1;
    if (self16) {
        unsigned sv0 = self16[(long)d0 * 64 + lane];
        ax0 = bflo(sv0); ay0 = bfhi(sv0);
        unsigned sv1 = self16[(long)(has1 ? d1 : d0) * 64 + lane];
        ax1 = bflo(sv1); ay1 = bfhi(sv1);
    } else {
        unsigned sv0 = g8[(long)d0 * 64 + lane];
        ax0 = up8lo(sv0); ay0 = up8hi(sv0);
        unsigned sv1 = g8[(long)(has1 ? d1 : d0) * 64 + lane];
        ax1 = up8lo(sv1); ay1 = up8hi(sv1);
    }

    for (int win = b0; win < e1; win += 64) {
        int m = e1 - win;
        if (m > 64) m = 64;
        int c = col[win + lane];  // lanes >= m load garbage; never consumed
        int j = 0;
        for (; j + 8 <= m; j += 8) {
            int s0 = __builtin_amdgcn_readlane(c, j);
            int s1 = __builtin_amdgcn_readlane(c, j + 1);
            int s2 = __builtin_amdgcn_readlane(c, j + 2);
            int s3 = __builtin_amdgcn_readlane(c, j + 3);
            int s4 = __builtin_amdgcn_readlane(c, j + 4);
            int s5 = __builtin_amdgcn_readlane(c, j + 5);
            int s6 = __builtin_amdgcn_readlane(c, j + 6);
            int s7 = __builtin_amdgcn_readlane(c, j + 7);
            unsigned v0 = g8[(long)s0 * 64 + lane];
            unsigned v1 = g8[(long)s1 * 64 + lane];
            unsigned v2 = g8[(long)s2 * 64 + lane];
            unsigned v3 = g8[(long)s3 * 64 + lane];
            unsigned v4 = g8[(long)s4 * 64 + lane];
            unsigned v5 = g8[(long)s5 * 64 + lane];
            unsigned v6 = g8[(long)s6 * 64 + lane];
            unsigned v7 = g8[(long)s7 * 64 + lane];
#pragma unroll
            for (int k = 0; k < 8; k++) {
                unsigned vv = (k == 0) ? v0 : (k == 1) ? v1 : (k == 2) ? v2 : (k == 3) ? v3
                            : (k == 4) ? v4 : (k == 5) ? v5 : (k == 6) ? v6 : v7;
                float w0 = (win + j + k < e0) ? 1.f : 0.f;  // wave-uniform select
                float w1 = 1.f - w0;
                float lx = up8lo(vv), ly = up8hi(vv);
                ax0 += lx * w0; ay0 += ly * w0;
                ax1 += lx * w1; ay1 += ly * w1;
            }
        }
        for (; j < m; j++) {
            int s = __builtin_amdgcn_readlane(c, j);
            unsigned vv = g8[(long)s * 64 + lane];
            float w0 = (win + j < e0) ? 1.f : 0.f;
            float w1 = 1.f - w0;
            float lx = up8lo(vv), ly = up8hi(vv);
            ax0 += lx * w0; ay0 += ly * w0;
            ax1 += lx * w1; ay1 += ly * w1;
        }
    }

    float dinv0 = 1.f / (float)(e0 - b0 + 1);
    float dinv1 = 1.f / (float)(e1 - e0 + 1);
    float rx0 = ax0 * dinv0, ry0 = ay0 * dinv0;
    float rx1 = ax1 * dinv1, ry1 = ay1 * dinv1;

    bool act = lane < (D / 2);
    unsigned p0 = act ? ((unsigned)f2bf(rx0) | ((unsigned)f2bf(ry0) << 16)) : 0u;
    o16[(long)d0 * 64 + lane] = p0;
    if (write8) o8[(long)d0 * 64 + lane] = act ? pk8(rx0, ry0) : (unsigned short)0;
    if (has1) {
        unsigned p1 = act ? ((unsigned)f2bf(rx1) | ((unsigned)f2bf(ry1) << 16)) : 0u;
        o16[(long)d1 * 64 + lane] = p1;
        if (write8) o8[(long)d1 * 64 + lane] = act ? pk8(rx1, ry1) : (unsigned short)0;
    }
}

// ---------------- fused epilogue: x1=u*W1^T, x2=v*Wc^T, norms, out ----------------
__global__ __launch_bounds__(256) void k_epi(const unsigned short* __restrict__ u16,
                                             const unsigned short* __restrict__ v16,
                                             const unsigned short* __restrict__ P,  // W1 then Wc frags
                                             const float* __restrict__ x0,
                                             float invlp1, float* __restrict__ out, int N) {
    int wave = threadIdx.x >> 6;
    int lane = threadIdx.x & 63;
    int quad = lane >> 4;
    int l16  = lane & 15;
    int rowbase = (blockIdx.x * 4 + wave) * 16;
    if (rowbase >= N) return;
    int arow = rowbase + l16;
    if (arow >= N) arow = N - 1;

    bf8v aU[4], aV[4];
    const unsigned short* ur = u16 + (long)arow * YSTRIDE;
    const unsigned short* vr = v16 + (long)arow * YSTRIDE;
#pragma unroll
    for (int kt = 0; kt < 4; kt++) {
        int k0 = kt * 32 + quad * 8;
        union { bf8v v; uint4 u; } a, b;
        a.u = *(const uint4*)(ur + k0);
        b.u = *(const uint4*)(vr + k0);
        aU[kt] = a.v;
        aV[kt] = b.v;
    }

    f4v accU[7], accV[7];
#pragma unroll
    for (int nt = 0; nt < 7; nt++) { accU[nt] = (f4v){0,0,0,0}; accV[nt] = (f4v){0,0,0,0}; }

    const uint4* bp = (const uint4*)P;
#pragma unroll
    for (int nt = 0; nt < 7; nt++) {
#pragma unroll
        for (int kt = 0; kt < 4; kt++) {
            union { uint4 u; bf8v v; } b1, b2;
            b1.u = bp[(nt * 4 + kt) * 64 + lane];
            b2.u = bp[(28 + nt * 4 + kt) * 64 + lane];
            accU[nt] = __builtin_amdgcn_mfma_f32_16x16x32_bf16(aU[kt], b1.v, accU[nt], 0, 0, 0);
            accV[nt] = __builtin_amdgcn_mfma_f32_16x16x32_bf16(aV[kt], b2.v, accV[nt], 0, 0, 0);
        }
    }

    float sU[4], sV[4];
#pragma unroll
    for (int i = 0; i < 4; i++) {
        float nu = 0.f, nv = 0.f;
#pragma unroll
        for (int nt = 0; nt < 7; nt++) {
            nu += accU[nt][i] * accU[nt][i];
            nv += accV[nt][i] * accV[nt][i];
        }
#pragma unroll
        for (int m = 1; m < 16; m <<= 1) {
            nu += __shfl_xor(nu, m);
            nv += __shfl_xor(nv, m);
        }
        sU[i] = invlp1 / fmaxf(sqrtf(nu), 1e-12f);
        sV[i] = invlp1 / fmaxf(sqrtf(nv), 1e-12f);
    }

#pragma unroll
    for (int nt = 0; nt < 7; nt++) {
        int cc = nt * 16 + l16;
        if (cc < D) {
#pragma unroll
            for (int i = 0; i < 4; i++) {
                int rr = rowbase + quad * 4 + i;
                if (rr < N) {
                    long idx = (long)rr * D + cc;
                    out[idx] = x0[idx] * invlp1 + accU[nt][i] * sU[i] + accV[nt][i] * sV[i];
                }
            }
        }
    }
}

// ---------------- launcher ----------------

extern "C" void kernel_launch(void* const* d_in, const int* in_sizes, int n_in,
                              void* d_out, int out_size, void* d_ws, size_t ws_size,
                              hipStream_t stream) {
    const float* features = (const float*)d_in[0];
    const float* W        = (const float*)d_in[1];
    const int*   src      = (const int*)d_in[2];
    const int*   dstv     = (const int*)d_in[3];

    int N = in_sizes[0] / D;            // 50000
    int E = in_sizes[2];                // 800000
    int L = in_sizes[1] / (D * D);      // 2 (composition assumes L==2)
    float invlp1 = 1.f / (float)(L + 1);
    int NBK = (N + BSIZE - 1) >> BSHIFT;

    char*  ws  = (char*)d_ws;
    size_t off = 0;
    auto alloc = [&](size_t bytes) -> void* {
        void* p = (void*)(ws + off);
        off += (bytes + 255) & ~(size_t)255;
        return p;
    };
    unsigned*       s8     = (unsigned*)alloc((size_t)N * 32 * sizeof(unsigned));  // fp8 rows (128 B)
    unsigned*       u8     = (unsigned*)alloc((size_t)N * 32 * sizeof(unsigned));  // fp8 rows (128 B)
    unsigned*       u16    = (unsigned*)alloc((size_t)N * 64 * sizeof(unsigned));  // bf16 rows (256 B)
    unsigned*       v16    = (unsigned*)alloc((size_t)N * 64 * sizeof(unsigned));  // bf16 rows (256 B)
    float*          Wc     = (float*)alloc((size_t)D * D * sizeof(float));
    unsigned short* wpack  = (unsigned short*)alloc((size_t)2 * 7 * 4 * 64 * 8 * sizeof(unsigned short));
    unsigned*       ebuf   = (unsigned*)alloc((size_t)E * sizeof(unsigned));
    int*            colb   = (int*)alloc((size_t)E * sizeof(int));
    int*            rowptr = (int*)alloc((size_t)(N + 1) * sizeof(int));
    int*            bcnt   = (int*)alloc((size_t)NBKMAX * sizeof(int));
    int*            boff   = (int*)alloc((size_t)(NBKMAX + 1) * sizeof(int));
    int*            bcur   = (int*)alloc((size_t)NBKMAX * sizeof(int));

    int nebk  = (E + EPB - 1) / EPB;
    int wtot  = 2 * 7 * 4 * 64;                 // 3584 fragment rows
    int packb = (N * 32 + 255) / 256;
    int wcb   = (D * D + 255) / 256;
    int prepb = (wtot + 255) / 256;

    hipMemsetAsync(bcnt, 0, (size_t)NBK * sizeof(int), stream);
    k_pre<<<packb + nebk + wcb, 256, 0, stream>>>(features, W, s8, Wc, bcnt, dstv,
                                                  N, E, NBK, packb, nebk);
    k_scanB_prep<<<1 + prepb, 256, 0, stream>>>(bcnt, boff, bcur, NBK, E, W, Wc, wpack, wtot);
    k_bucketC<<<nebk, 256, 0, stream>>>(src, dstv, bcur, ebuf, E, NBK);
    k_bucketD<<<NBK, 256, 0, stream>>>(ebuf, boff, colb, rowptr, N, NBK, E);

    int spmmblocks = (N + 7) / 8;  // 4 waves x 2 nodes per block
    // u = A*s0: gather fp8 s8, write u8 (fp8) + u16 (bf16)
    k_spmm<<<spmmblocks, 256, 0, stream>>>((const unsigned short*)s8, rowptr, colb,
                                           (const unsigned*)nullptr,
                                           (unsigned short*)u8, u16, 1, N);
    // v = A*u: gather fp8 u8 (self from bf16 u16), write v16 (bf16)
    k_spmm<<<spmmblocks, 256, 0, stream>>>((const unsigned short*)u8, rowptr, colb,
                                           u16, (unsigned short*)nullptr, v16, 0, N);

    int nrowtiles = (N + 15) / 16;
    int epiblocks = (nrowtiles + 3) / 4;
    k_epi<<<epiblocks, 256, 0, stream>>>((const unsigned short*)u16, (const unsigned short*)v16,
                                         wpack, features, invlp1, (float*)d_out, N);
}